// Round 1
// baseline (2975.455 us; speedup 1.0000x reference)
//
#include <hip/hip_runtime.h>

#define HH 20

__device__ __forceinline__ float sigm(float x) { return 1.0f / (1.0f + __expf(-x)); }
__device__ __forceinline__ float tnh(float x)  { return 1.0f - 2.0f / (__expf(2.0f * x) + 1.0f); }

__global__ __launch_bounds__(64, 1)
void lstm2_kernel(const float* __restrict__ x_in,
                  const float* __restrict__ Wih1,
                  const float* __restrict__ Whh1,
                  const float* __restrict__ bih1,
                  const float* __restrict__ bhh1,
                  const float* __restrict__ Wih2,
                  const float* __restrict__ Whh2,
                  const float* __restrict__ bih2,
                  const float* __restrict__ bhh2,
                  float* __restrict__ out,
                  int T, int F)
{
    const int tid = threadIdx.x;
    const int e   = tid >> 5;          // which batch of this wave (0/1)
    const int j   = tid & 31;          // lane within 32-lane group
    const int b   = blockIdx.x * 2 + e;

    // [parity][group][ h1: 0..19 (pad 24) | c1: 24..43 (pad 48) ]
    __shared__ float  sb[2][2][48];
    __shared__ float4 g2w[2];
    __shared__ float  c2bc[2];

    for (int i = tid; i < 2 * 2 * 48; i += 64) ((float*)sb)[i] = 0.0f;
    if (tid < 2) { g2w[tid] = make_float4(0.f, 0.f, 0.f, 0.f); c2bc[tid] = 0.0f; }
    __syncthreads();

    // ---- per-lane weights ----
    float w0[HH], w1[HH], w2[HH], w3[HH];
    float wx0 = 0, wx1 = 0, wx2 = 0, wx3 = 0, bs0 = 0, bs1 = 0, bs2 = 0, bs3 = 0;
    if (j < HH) {
        int r0 = j, r1 = 20 + j, r2 = 40 + j, r3 = 60 + j;
        #pragma unroll
        for (int k = 0; k < HH; k++) {
            w0[k] = Whh1[r0 * HH + k]; w1[k] = Whh1[r1 * HH + k];
            w2[k] = Whh1[r2 * HH + k]; w3[k] = Whh1[r3 * HH + k];
        }
        wx0 = Wih1[r0]; wx1 = Wih1[r1]; wx2 = Wih1[r2]; wx3 = Wih1[r3];
        bs0 = bih1[r0] + bhh1[r0]; bs1 = bih1[r1] + bhh1[r1];
        bs2 = bih1[r2] + bhh1[r2]; bs3 = bih1[r3] + bhh1[r3];
    } else if (j < 24) {
        int g = j - 20;
        #pragma unroll
        for (int k = 0; k < HH; k++) { w0[k] = Wih2[g * HH + k]; w1[k] = 0; w2[k] = 0; w3[k] = 0; }
        wx0 = Whh2[g];               // multiplies h2 (scalar, O=1)
        bs0 = bih2[g] + bhh2[g];
    } else {
        #pragma unroll
        for (int k = 0; k < HH; k++) { w0[k] = 0; w1[k] = 0; w2[k] = 0; w3[k] = 0; }
    }

    float cmy  = 0.0f;   // c1[j] (j<20) | c2 (lanes 20..23, replicated)
    float h2my = 0.0f;   // h2 (lanes 20..23, replicated)

    const long xbase = (long)b * T;
    const long obase = (long)b * (T + F);

    float xr = x_in[xbase];

    // ================= main scan; layer-2 runs 1 step behind =================
    for (int t = 0; t < T; ++t) {
        const int p = t & 1;
        const float* rb   = &sb[p][e][0];
        float*       wbuf = &sb[p ^ 1][e][0];

        const int tn = (t + 1 < T) ? (t + 1) : (T - 1);
        const float xnext = x_in[xbase + tn];   // prefetch

        // layer-1 lanes read h1(t-1); layer-2 lanes read c1(t-1)
        const float4* vb = (const float4*)((j < HH) ? rb : (rb + 24));
        float4 q0 = vb[0], q1 = vb[1], q2 = vb[2], q3 = vb[3], q4 = vb[4];
        float v[HH] = { q0.x,q0.y,q0.z,q0.w, q1.x,q1.y,q1.z,q1.w,
                        q2.x,q2.y,q2.z,q2.w, q3.x,q3.y,q3.z,q3.w,
                        q4.x,q4.y,q4.z,q4.w };

        const float xin = (j < HH) ? xr : h2my;
        float a0 = bs0 + wx0 * xin;
        float a1 = bs1 + wx1 * xr;
        float a2 = bs2 + wx2 * xr;
        float a3 = bs3 + wx3 * xr;
        #pragma unroll
        for (int k = 0; k < HH; k++) {
            a0 += w0[k] * v[k]; a1 += w1[k] * v[k];
            a2 += w2[k] * v[k]; a3 += w3[k] * v[k];
        }

        if (j < HH) {
            float ig = sigm(a0), fg = sigm(a1), gg = tnh(a2), og = sigm(a3);
            float cn = fg * cmy + ig * gg;
            float hn = og * tnh(cn);
            cmy = cn;
            wbuf[j]      = hn;
            wbuf[24 + j] = cn;
        } else if (j < 24) {
            int g = j - 20;
            float act = (g == 2) ? tnh(a0) : sigm(a0);
            ((float*)&g2w[e])[g] = act;
        }
        __syncthreads();
        if (j >= HH && j < 24 && t > 0) {
            float4 gg = g2w[e];                    // (sig i, sig f, tanh g, sig o)
            float c2n = gg.y * cmy + gg.x * gg.z;  // layer-2 step t-1
            h2my = gg.w * tnh(c2n);
            cmy  = c2n;
            if (j == HH) out[obase + (t - 1)] = c2n;
        }
        xr = xnext;
    }

    // ================= drain: layer-2 step T-1 =================
    {
        const float* rb = &sb[T & 1][e][0];
        if (j >= HH && j < 24) {
            const float4* vb = (const float4*)(rb + 24);
            float4 q0 = vb[0], q1 = vb[1], q2 = vb[2], q3 = vb[3], q4 = vb[4];
            float v[HH] = { q0.x,q0.y,q0.z,q0.w, q1.x,q1.y,q1.z,q1.w,
                            q2.x,q2.y,q2.z,q2.w, q3.x,q3.y,q3.z,q3.w,
                            q4.x,q4.y,q4.z,q4.w };
            float a0 = bs0 + wx0 * h2my;
            #pragma unroll
            for (int k = 0; k < HH; k++) a0 += w0[k] * v[k];
            int g = j - 20;
            float act = (g == 2) ? tnh(a0) : sigm(a0);
            ((float*)&g2w[e])[g] = act;
        }
        __syncthreads();
        if (j >= HH && j < 24) {
            float4 gg = g2w[e];
            float c2n = gg.y * cmy + gg.x * gg.z;
            h2my = gg.w * tnh(c2n);
            cmy  = c2n;
            if (j == HH) { out[obase + (T - 1)] = c2n; c2bc[e] = c2n; }
        }
        __syncthreads();
    }

    // ================= future phase (not pipelined) =================
    int p = T & 1;
    for (int i = 0; i < F; ++i) {
        const float xb = c2bc[e];                 // c2 of previous step
        const float* rb   = &sb[p][e][0];
        float*       wbuf = &sb[p ^ 1][e][0];

        if (j < HH) {
            const float4* vb = (const float4*)rb;
            float4 q0 = vb[0], q1 = vb[1], q2 = vb[2], q3 = vb[3], q4 = vb[4];
            float v[HH] = { q0.x,q0.y,q0.z,q0.w, q1.x,q1.y,q1.z,q1.w,
                            q2.x,q2.y,q2.z,q2.w, q3.x,q3.y,q3.z,q3.w,
                            q4.x,q4.y,q4.z,q4.w };
            float a0 = bs0 + wx0 * xb;
            float a1 = bs1 + wx1 * xb;
            float a2 = bs2 + wx2 * xb;
            float a3 = bs3 + wx3 * xb;
            #pragma unroll
            for (int k = 0; k < HH; k++) {
                a0 += w0[k] * v[k]; a1 += w1[k] * v[k];
                a2 += w2[k] * v[k]; a3 += w3[k] * v[k];
            }
            float ig = sigm(a0), fg = sigm(a1), gg = tnh(a2), og = sigm(a3);
            float cn = fg * cmy + ig * gg;
            float hn = og * tnh(cn);
            cmy = cn;
            wbuf[j]      = hn;
            wbuf[24 + j] = cn;
        }
        __syncthreads();
        if (j >= HH && j < 24) {
            const float4* vb = (const float4*)(wbuf + 24);   // c1 of THIS step
            float4 q0 = vb[0], q1 = vb[1], q2 = vb[2], q3 = vb[3], q4 = vb[4];
            float v[HH] = { q0.x,q0.y,q0.z,q0.w, q1.x,q1.y,q1.z,q1.w,
                            q2.x,q2.y,q2.z,q2.w, q3.x,q3.y,q3.z,q3.w,
                            q4.x,q4.y,q4.z,q4.w };
            float a0 = bs0 + wx0 * h2my;
            #pragma unroll
            for (int k = 0; k < HH; k++) a0 += w0[k] * v[k];
            int g = j - 20;
            float act = (g == 2) ? tnh(a0) : sigm(a0);
            ((float*)&g2w[e])[g] = act;
        }
        __syncthreads();
        if (j >= HH && j < 24) {
            float4 gg = g2w[e];
            float c2n = gg.y * cmy + gg.x * gg.z;
            h2my = gg.w * tnh(c2n);
            cmy  = c2n;
            if (j == HH) { out[obase + T + i] = c2n; c2bc[e] = c2n; }
        }
        __syncthreads();
        p ^= 1;
    }
}

extern "C" void kernel_launch(void* const* d_in, const int* in_sizes, int n_in,
                              void* d_out, int out_size, void* d_ws, size_t ws_size,
                              hipStream_t stream) {
    const float* x    = (const float*)d_in[0];
    const float* Wih1 = (const float*)d_in[1];
    const float* Whh1 = (const float*)d_in[2];
    const float* bih1 = (const float*)d_in[3];
    const float* bhh1 = (const float*)d_in[4];
    const float* Wih2 = (const float*)d_in[5];
    const float* Whh2 = (const float*)d_in[6];
    const float* bih2 = (const float*)d_in[7];
    const float* bhh2 = (const float*)d_in[8];
    float* out = (float*)d_out;

    const int B = 1024;
    const int T = in_sizes[0] / B;        // 4096
    const int F = out_size / B - T;       // 16

    hipLaunchKernelGGL(lstm2_kernel, dim3(B / 2), dim3(64), 0, stream,
                       x, Wih1, Whh1, bih1, bhh1, Wih2, Whh2, bih2, bhh2, out, T, F);
}

// Round 2
// 2478.542 us; speedup vs baseline: 1.2005x; 1.2005x over previous
//
#include <hip/hip_runtime.h>

#define HH 20

__device__ __forceinline__ float sigm(float x) { return 1.0f / (1.0f + __expf(-x)); }
__device__ __forceinline__ float tnh(float x)  { return 1.0f - 2.0f / (__expf(2.0f * x) + 1.0f); }

template <int CTRL>
__device__ __forceinline__ float qperm(float x) {
    return __int_as_float(__builtin_amdgcn_mov_dpp(__float_as_int(x), CTRL, 0xF, 0xF, false));
}

#define FMA_F4(A, W, V) \
    A = fmaf((W).x, (V).x, (A)); \
    A = fmaf((W).y, (V).y, (A)); \
    A = fmaf((W).z, (V).z, (A)); \
    A = fmaf((W).w, (V).w, (A));

#define DOT20(A, Wa, Wb, Wc, Wd, We) \
    FMA_F4(A, Wa, q0) FMA_F4(A, Wb, q1) FMA_F4(A, Wc, q2) FMA_F4(A, Wd, q3) FMA_F4(A, We, q4)

__global__ __launch_bounds__(64, 1)
void lstm2_kernel(const float* __restrict__ x_in,
                  const float* __restrict__ Wih1,
                  const float* __restrict__ Whh1,
                  const float* __restrict__ bih1,
                  const float* __restrict__ bhh1,
                  const float* __restrict__ Wih2,
                  const float* __restrict__ Whh2,
                  const float* __restrict__ bih2,
                  const float* __restrict__ bhh2,
                  float* __restrict__ out,
                  int T, int F)
{
    const int tid = threadIdx.x;
    const int e   = tid >> 5;          // which chain of this wave (0/1)
    const int j   = tid & 31;          // lane within 32-lane group
    const int b   = blockIdx.x * 2 + e;

    // [parity][group][ h1: 0..19 | c1: 24..43 ] (48-float stride)
    __shared__ float sb[2][2][48];
    __shared__ float c2bc[2];

    for (int i = tid; i < 2 * 2 * 48; i += 64) ((float*)sb)[i] = 0.0f;
    if (tid < 2) c2bc[tid] = 0.0f;
    __builtin_amdgcn_wave_barrier();

    // ---- per-lane weights: 20 named float4 registers (NO arrays -> no scratch) ----
    const float4 *P0, *P1, *P2, *P3;
    if (j < HH) {
        P0 = (const float4*)(Whh1 + j * HH);
        P1 = (const float4*)(Whh1 + (HH + j) * HH);
        P2 = (const float4*)(Whh1 + (2 * HH + j) * HH);
        P3 = (const float4*)(Whh1 + (3 * HH + j) * HH);
    } else if (j < 24) {
        P0 = (const float4*)(Wih2 + (j - HH) * HH);
        P1 = P2 = P3 = (const float4*)Whh1;   // valid dummy rows
    } else {
        P0 = P1 = P2 = P3 = (const float4*)Whh1;
    }
    float4 w0a = P0[0], w0b = P0[1], w0c = P0[2], w0d = P0[3], w0e = P0[4];
    float4 w1a = P1[0], w1b = P1[1], w1c = P1[2], w1d = P1[3], w1e = P1[4];
    float4 w2a = P2[0], w2b = P2[1], w2c = P2[2], w2d = P2[3], w2e = P2[4];
    float4 w3a = P3[0], w3b = P3[1], w3c = P3[2], w3d = P3[3], w3e = P3[4];

    float wx0 = 0, wx1 = 0, wx2 = 0, wx3 = 0, bs0 = 0, bs1 = 0, bs2 = 0, bs3 = 0;
    if (j < HH) {
        wx0 = Wih1[j]; wx1 = Wih1[HH + j]; wx2 = Wih1[2 * HH + j]; wx3 = Wih1[3 * HH + j];
        bs0 = bih1[j] + bhh1[j];
        bs1 = bih1[HH + j] + bhh1[HH + j];
        bs2 = bih1[2 * HH + j] + bhh1[2 * HH + j];
        bs3 = bih1[3 * HH + j] + bhh1[3 * HH + j];
    } else if (j < 24) {
        int g = j - HH;
        wx0 = Whh2[g];                 // multiplies h2 (scalar, O=1)
        bs0 = bih2[g] + bhh2[g];
    }

    float cmy  = 0.0f;   // c1[j] (j<20) | c2 (lanes 20..23, replicated)
    float h2my = 0.0f;   // h2 (lanes 20..23, replicated)
    float actp = 0.0f;   // layer-2 own-gate activation from previous iter

    const long xbase = (long)b * T;
    const long obase = (long)b * (T + F);
    const int  roff  = (j < HH) ? 0 : 24;   // layer-1 reads h-block, layer-2 reads c-block

    // 3-deep x prefetch pipeline
    float xr = x_in[xbase];
    float x1 = x_in[xbase + (T > 1 ? 1 : 0)];
    float x2 = x_in[xbase + (T > 2 ? 2 : 0)];

    // ================= main scan; layer-2 combine runs 2 steps behind =================
    for (int t = 0; t < T; ++t) {
        const float* rb   = &sb[t & 1][e][0];
        float*       wbuf = &sb[(t & 1) ^ 1][e][0];

        // issue the h/c broadcast reads first (latency overlaps the combine below)
        const float4* vb = (const float4*)(rb + roff);
        float4 q0 = vb[0], q1 = vb[1], q2 = vb[2], q3 = vb[3], q4 = vb[4];

        int tn = t + 3; tn = (tn < T) ? tn : (T - 1);
        const float xf = x_in[xbase + tn];

        // layer-2 combine for step s = t-2 (uses actp from previous iteration)
        if (j >= HH) {
            float ai = qperm<0x00>(actp), af = qperm<0x55>(actp);
            float ag = qperm<0xAA>(actp), ao = qperm<0xFF>(actp);
            if (t >= 2) {
                float c2n = af * cmy + ai * ag;
                h2my = ao * tnh(c2n);
                cmy  = c2n;
                if (j == HH) out[obase + t - 2] = c2n;
            }
        }

        const float xin = (j < HH) ? xr : h2my;
        float a0 = fmaf(wx0, xin, bs0);
        float a1 = fmaf(wx1, xr, bs1);
        float a2 = fmaf(wx2, xr, bs2);
        float a3 = fmaf(wx3, xr, bs3);
        DOT20(a0, w0a, w0b, w0c, w0d, w0e)
        DOT20(a1, w1a, w1b, w1c, w1d, w1e)
        DOT20(a2, w2a, w2b, w2c, w2d, w2e)
        DOT20(a3, w3a, w3b, w3c, w3d, w3e)

        if (j < HH) {
            float ig = sigm(a0), fg = sigm(a1), gg = tnh(a2), og = sigm(a3);
            float cn = fg * cmy + ig * gg;
            float hn = og * tnh(cn);
            cmy = cn;
            wbuf[j]      = hn;
            wbuf[24 + j] = cn;
        } else {
            actp = (j == HH + 2) ? tnh(a0) : sigm(a0);   // lane 22 is gate 'g' (tanh)
        }
        __builtin_amdgcn_wave_barrier();
        xr = x1; x1 = x2; x2 = xf;
    }

    // ================= drain =================
    // combine s = T-2
    if (j >= HH) {
        float ai = qperm<0x00>(actp), af = qperm<0x55>(actp);
        float ag = qperm<0xAA>(actp), ao = qperm<0xFF>(actp);
        float c2n = af * cmy + ai * ag;
        h2my = ao * tnh(c2n);
        cmy  = c2n;
        if (j == HH) out[obase + T - 2] = c2n;
    }
    // full layer-2 step s = T-1 (c1(T-1) sits in sb[T&1])
    if (j >= HH) {
        const float4* vb = (const float4*)(&sb[T & 1][e][24]);
        float4 q0 = vb[0], q1 = vb[1], q2 = vb[2], q3 = vb[3], q4 = vb[4];
        float a0 = fmaf(wx0, h2my, bs0);
        DOT20(a0, w0a, w0b, w0c, w0d, w0e)
        float actn = (j == HH + 2) ? tnh(a0) : sigm(a0);
        float ai = qperm<0x00>(actn), af = qperm<0x55>(actn);
        float ag = qperm<0xAA>(actn), ao = qperm<0xFF>(actn);
        float c2n = af * cmy + ai * ag;
        h2my = ao * tnh(c2n);
        cmy  = c2n;
        if (j == HH) { out[obase + T - 1] = c2n; c2bc[e] = c2n; }
    }
    __builtin_amdgcn_wave_barrier();

    // ================= future phase (serial, F=16) =================
    int p = T & 1;
    for (int i = 0; i < F; ++i) {
        const float xb = c2bc[e];
        const float* rb   = &sb[p][e][0];
        float*       wbuf = &sb[p ^ 1][e][0];

        if (j < HH) {
            const float4* vb = (const float4*)rb;
            float4 q0 = vb[0], q1 = vb[1], q2 = vb[2], q3 = vb[3], q4 = vb[4];
            float a0 = fmaf(wx0, xb, bs0);
            float a1 = fmaf(wx1, xb, bs1);
            float a2 = fmaf(wx2, xb, bs2);
            float a3 = fmaf(wx3, xb, bs3);
            DOT20(a0, w0a, w0b, w0c, w0d, w0e)
            DOT20(a1, w1a, w1b, w1c, w1d, w1e)
            DOT20(a2, w2a, w2b, w2c, w2d, w2e)
            DOT20(a3, w3a, w3b, w3c, w3d, w3e)
            float ig = sigm(a0), fg = sigm(a1), gg = tnh(a2), og = sigm(a3);
            float cn = fg * cmy + ig * gg;
            float hn = og * tnh(cn);
            cmy = cn;
            wbuf[j]      = hn;
            wbuf[24 + j] = cn;
        }
        __builtin_amdgcn_wave_barrier();
        if (j >= HH) {
            const float4* vb = (const float4*)(wbuf + 24);   // c1 of THIS step
            float4 q0 = vb[0], q1 = vb[1], q2 = vb[2], q3 = vb[3], q4 = vb[4];
            float a0 = fmaf(wx0, h2my, bs0);
            DOT20(a0, w0a, w0b, w0c, w0d, w0e)
            float actn = (j == HH + 2) ? tnh(a0) : sigm(a0);
            float ai = qperm<0x00>(actn), af = qperm<0x55>(actn);
            float ag = qperm<0xAA>(actn), ao = qperm<0xFF>(actn);
            float c2n = af * cmy + ai * ag;
            h2my = ao * tnh(c2n);
            cmy  = c2n;
            if (j == HH) { out[obase + T + i] = c2n; c2bc[e] = c2n; }
        }
        __builtin_amdgcn_wave_barrier();
        p ^= 1;
    }
}

extern "C" void kernel_launch(void* const* d_in, const int* in_sizes, int n_in,
                              void* d_out, int out_size, void* d_ws, size_t ws_size,
                              hipStream_t stream) {
    const float* x    = (const float*)d_in[0];
    const float* Wih1 = (const float*)d_in[1];
    const float* Whh1 = (const float*)d_in[2];
    const float* bih1 = (const float*)d_in[3];
    const float* bhh1 = (const float*)d_in[4];
    const float* Wih2 = (const float*)d_in[5];
    const float* Whh2 = (const float*)d_in[6];
    const float* bih2 = (const float*)d_in[7];
    const float* bhh2 = (const float*)d_in[8];
    float* out = (float*)d_out;

    const int B = 1024;
    const int T = in_sizes[0] / B;        // 4096
    const int F = out_size / B - T;       // 16

    hipLaunchKernelGGL(lstm2_kernel, dim3(B / 2), dim3(64), 0, stream,
                       x, Wih1, Whh1, bih1, bhh1, Wih2, Whh2, bih2, bhh2, out, T, F);
}